// Round 8
// baseline (354.484 us; speedup 1.0000x reference)
//
#include <hip/hip_runtime.h>
#include <hip/hip_bf16.h>
#include <cstdint>
#include <cstddef>

typedef __bf16 bf16_t;
typedef __bf16 bf16x8 __attribute__((ext_vector_type(8)));
typedef __bf16 bf16x4 __attribute__((ext_vector_type(4)));
typedef float  f32x4  __attribute__((ext_vector_type(4)));
typedef float  f32x16 __attribute__((ext_vector_type(16)));

#define AS1(p) ((const __attribute__((address_space(1))) unsigned int*)(p))
#define AS3(p) ((__attribute__((address_space(3))) unsigned int*)(p))

#if __has_builtin(__builtin_amdgcn_rcpf)
  #define FAST_RCP(x) __builtin_amdgcn_rcpf(x)
#else
  #define FAST_RCP(x) (1.0f / (x))
#endif

// Fast exact-gelu: Phi(v) via Abramowitz-Stegun 7.1.26 erf (|err| <= 1.5e-7).
__device__ __forceinline__ float gelu_fast(float v) {
    float z = fabsf(v) * 0.70710678118654752440f;
    float t = FAST_RCP(fmaf(0.3275911f, z, 1.0f));
    float p = fmaf(t, 1.061405429f, -1.453152027f);
    p = fmaf(t, p, 1.421413741f);
    p = fmaf(t, p, -0.284496736f);
    p = fmaf(t, p, 0.254829592f);
    p *= t;
    float e = p * exp2f(-z * z * 1.4426950408889634f);
    float phi = (v >= 0.0f) ? fmaf(-0.5f, e, 1.0f) : (0.5f * e);
    return v * phi;
}

// ---------- fused prep: W1 f32->bf16 | x -> xT bf16 | attn zero-init ----------
__global__ void k_prep(const float* __restrict__ W1, bf16_t* __restrict__ W1bf,
                       const float* __restrict__ x, bf16_t* __restrict__ xT,
                       float* __restrict__ attn) {
    __shared__ bf16_t t[64][66];
    int bx = blockIdx.x;
    int tid = threadIdx.x;
    if (bx < 9216) {
        int i = bx * 256 + tid;
        f32x4 v = ((const f32x4*)W1)[i];
        bf16x4 o;
        o[0] = (bf16_t)v[0]; o[1] = (bf16_t)v[1];
        o[2] = (bf16_t)v[2]; o[3] = (bf16_t)v[3];
        ((bf16x4*)W1bf)[i] = o;
        return;
    }
    if (bx >= 10752) {   // 64 blocks zero attn (65536 f32)
        int i = (bx - 10752) * 256 + tid;
        ((f32x4*)attn)[i] = f32x4{0.f, 0.f, 0.f, 0.f};
        return;
    }
    int bx2 = bx - 9216;
    int ct = bx2 % 12, ht = (bx2 / 12) % 4, b = bx2 / 48;
    int col = tid & 63, rr = tid >> 6;
    const float* xb = x + ((size_t)b * 768 + (size_t)ct * 64) * 256 + ht * 64;
    #pragma unroll
    for (int r = 0; r < 16; ++r) {
        int c = r * 4 + rr;
        t[c][col] = (bf16_t)xb[(size_t)c * 256 + col];
    }
    __syncthreads();
    bf16_t* xTb = xT + ((size_t)b * 256 + (size_t)ht * 64) * 768 + ct * 64;
    #pragma unroll
    for (int r = 0; r < 16; ++r) {
        int hw = r * 4 + rr;
        xTb[(size_t)hw * 768 + col] = t[col][hw];
    }
}

// ---------- fused grouped-GEMM + bias + fast-gelu + W2 reduction -> attn partials ----------
// T1: g = bid&7 (group per XCD). T2: chunk^(row&7) swizzle, source-pre-swizzled.
// T3+T4 (this round): 2 phases per K-tile, TRIPLE-buffered LDS (compute t, t+1 landed,
// t+2 staging), counted vmcnt(6) at tile exit — never drained mid-loop; loads stay in
// flight across barriers. T5: setprio(1) around each phase's MFMA cluster (role-split
// waves now exist for the scheduler to arbitrate — m218b regime gate).
// Buffer k at smem + k*49152: A-tile at +0 (16 KB), B-tile at +16384 (32 KB).
__global__ __launch_bounds__(512) void k_attn_gemm(
    const bf16_t* __restrict__ W1bf, const bf16_t* __restrict__ xTbf,
    const float* __restrict__ b1, const float* __restrict__ W2,
    float* __restrict__ attn)
{
    extern __shared__ char smem[];
    float* attn_s = (float*)(smem + 147456);   // after 3 x 48 KB buffers

    const int tid = threadIdx.x;
    const int l = tid & 63, w = tid >> 6;
    const int wm = w >> 2, wn = w & 3;           // 2 x 4 waves, 64x64 tile each
    const int bid = blockIdx.x;
    const int g     = bid & 7;
    const int local = bid >> 3;
    const int chunk = local / 24;
    const int sub   = local % 24;
    const int mt    = sub >> 1;
    const int b     = chunk * 2 + (sub & 1);

    const bf16_t* gAs = W1bf + ((size_t)g * 1536 + (size_t)mt * 128) * 768;
    const bf16_t* gBs = xTbf + (size_t)b * 256 * 768;

    if (tid < 256) attn_s[tid] = 0.0f;

    // ---- hoisted staging offsets (per-lane, tile-invariant) ----
    int voffA[2], ldsA[2], voffB[4], ldsB[4];
    #pragma unroll
    for (int i = 0; i < 2; ++i) {
        int q = i * 512 + tid, row = q >> 3, sc = (q & 7) ^ (row & 7);
        voffA[i] = row * 768 + sc * 8;
        ldsA[i] = q * 16;
    }
    #pragma unroll
    for (int i = 0; i < 4; ++i) {
        int q = i * 512 + tid, row = q >> 3, sc = (q & 7) ^ (row & 7);
        voffB[i] = row * 768 + sc * 8;
        ldsB[i] = q * 16;
    }

    // ---- hoisted LDS read offsets (tile-invariant, REGION-relative) ----
    // A/B frag for 32x32x16: row = l&31, k-chunk = l>>5 within K=16 slice.
    const int hi = l >> 5;
    uint32_t aoff[4][2], boff[4][2];
    #pragma unroll
    for (int ks = 0; ks < 4; ++ks) {
        const int c = ks * 2 + hi;
        #pragma unroll
        for (int mi = 0; mi < 2; ++mi) {
            int r = wm * 64 + mi * 32 + (l & 31);
            aoff[ks][mi] = (uint32_t)((r * 8 + (c ^ (r & 7))) * 16);
        }
        #pragma unroll
        for (int ni = 0; ni < 2; ++ni) {
            int r = wn * 64 + ni * 32 + (l & 31);
            boff[ks][ni] = (uint32_t)((r * 8 + (c ^ (r & 7))) * 16);
        }
    }

    f32x16 acc[2][2];
    #pragma unroll
    for (int mi = 0; mi < 2; ++mi)
        #pragma unroll
        for (int ni = 0; ni < 2; ++ni)
            acc[mi][ni] = (f32x16)(0.0f);

    // 3 loads per half: H1 = {A0, A1, B0}; H2 = {B1, B2, B3} + base advance.
    auto STAGE_H1 = [&](int sb) {
        __builtin_amdgcn_global_load_lds(AS1(gAs + voffA[0]),
            AS3(smem + sb + ldsA[0]), 16, 0, 0);
        __builtin_amdgcn_global_load_lds(AS1(gAs + voffA[1]),
            AS3(smem + sb + ldsA[1]), 16, 0, 0);
        __builtin_amdgcn_global_load_lds(AS1(gBs + voffB[0]),
            AS3(smem + sb + 16384 + ldsB[0]), 16, 0, 0);
    };
    auto STAGE_H2 = [&](int sb) {
        #pragma unroll
        for (int i = 1; i < 4; ++i)
            __builtin_amdgcn_global_load_lds(AS1(gBs + voffB[i]),
                AS3(smem + sb + 16384 + ldsB[i]), 16, 0, 0);
        gAs += 64; gBs += 64;   // advance to next staged tile (uniform, SALU)
    };

    // One phase: 8 ds_read + stage-half issue, barrier, setprio-wrapped 8 MFMA.
    // (trailing barrier placed by caller — tile exit inserts vmcnt first)
    auto PHASE = [&](int cb, int k2, bool do_stage, int sb, int half) {
        bf16x8 fa0[2], fb0[2], fa1[2], fb1[2];
        #pragma unroll
        for (int mi = 0; mi < 2; ++mi)
            fa0[mi] = *(const bf16x8*)(smem + cb + aoff[k2 * 2][mi]);
        #pragma unroll
        for (int ni = 0; ni < 2; ++ni)
            fb0[ni] = *(const bf16x8*)(smem + cb + 16384 + boff[k2 * 2][ni]);
        #pragma unroll
        for (int mi = 0; mi < 2; ++mi)
            fa1[mi] = *(const bf16x8*)(smem + cb + aoff[k2 * 2 + 1][mi]);
        #pragma unroll
        for (int ni = 0; ni < 2; ++ni)
            fb1[ni] = *(const bf16x8*)(smem + cb + 16384 + boff[k2 * 2 + 1][ni]);
        if (do_stage) { if (half == 0) STAGE_H1(sb); else STAGE_H2(sb); }
        __builtin_amdgcn_s_barrier();
        __builtin_amdgcn_s_setprio(1);
        #pragma unroll
        for (int mi = 0; mi < 2; ++mi)
            #pragma unroll
            for (int ni = 0; ni < 2; ++ni)
                acc[mi][ni] = __builtin_amdgcn_mfma_f32_32x32x16_bf16(
                    fa0[mi], fb0[ni], acc[mi][ni], 0, 0, 0);
        #pragma unroll
        for (int mi = 0; mi < 2; ++mi)
            #pragma unroll
            for (int ni = 0; ni < 2; ++ni)
                acc[mi][ni] = __builtin_amdgcn_mfma_f32_32x32x16_bf16(
                    fa1[mi], fb1[ni], acc[mi][ni], 0, 0, 0);
        __builtin_amdgcn_s_setprio(0);
    };

    // ---- prologue: stage t0 -> buf0, t1 -> buf1 (12 loads in flight) ----
    STAGE_H1(0);      STAGE_H2(0);
    STAGE_H1(49152);  STAGE_H2(49152);
    asm volatile("s_waitcnt vmcnt(6)" ::: "memory");   // t0 landed (own 6)
    __builtin_amdgcn_s_barrier();                      // everyone's t0 landed

    // ---- main loop: 12 K-tiles, 2 phases each, fully unrolled (static bases) ----
    #pragma unroll
    for (int t = 0; t < 12; ++t) {
        const int cb = (t % 3) * 49152;            // compute buffer
        const int sb = ((t + 2) % 3) * 49152;      // stage target (t+2)
        const bool st = (t < 10);

        PHASE(cb, 0, st, sb, 0);
        __builtin_amdgcn_s_barrier();
        PHASE(cb, 1, st, sb, 1);
        // tile exit: ensure NEXT tile's 6 loads landed; keep t+2's in flight.
        if (t < 10)       asm volatile("s_waitcnt vmcnt(6)" ::: "memory");
        else if (t == 10) asm volatile("s_waitcnt vmcnt(0)" ::: "memory");
        __builtin_amdgcn_s_barrier();
    }

    // ---- epilogue: bias + gelu + W2 dot over the 128 local D-rows ----
    // 32x32 C/D: col = l&31, row = (rg&3) + 8*(rg>>2) + 4*(l>>5)  [m74/m101]
    float partial[2] = {0.f, 0.f};
    #pragma unroll
    for (int mi = 0; mi < 2; ++mi) {
        const int dbase = g * 1536 + mt * 128 + wm * 64 + mi * 32 + hi * 4;
        #pragma unroll
        for (int rq = 0; rq < 4; ++rq) {
            f32x4 b1v = *(const f32x4*)&b1[dbase + rq * 8];
            f32x4 w2v = *(const f32x4*)&W2[dbase + rq * 8];
            #pragma unroll
            for (int j = 0; j < 4; ++j) {
                const int rg = rq * 4 + j;
                #pragma unroll
                for (int ni = 0; ni < 2; ++ni) {
                    float h = acc[mi][ni][rg] + b1v[j];
                    partial[ni] += gelu_fast(h) * w2v[j];
                }
            }
        }
    }
    #pragma unroll
    for (int ni = 0; ni < 2; ++ni)
        partial[ni] += __shfl_xor(partial[ni], 32, 64);
    if (l < 32) {
        #pragma unroll
        for (int ni = 0; ni < 2; ++ni)
            atomicAdd(&attn_s[wn * 64 + ni * 32 + l], partial[ni]);
    }
    __syncthreads();
    if (tid < 256)
        atomicAdd(&attn[((size_t)b * 8 + g) * 256 + tid], attn_s[tid]);
}

// ---------- weighted mean pool ----------
__global__ void k_pool(const float* __restrict__ x, const float* __restrict__ attn,
                       const float* __restrict__ b2, float* __restrict__ out)
{
    int tid = threadIdx.x;
    int l = tid & 63, w = tid >> 6;
    int gidx = blockIdx.x * 4 + w;
    int b = gidx / 768;
    f32x4 xv = ((const f32x4*)(x + (size_t)gidx * 256))[l];
    float accg[8];
    #pragma unroll
    for (int g = 0; g < 8; ++g) {
        f32x4 av = ((const f32x4*)(attn + ((size_t)b * 8 + g) * 256))[l];
        float bb = b2[g];
        accg[g] = xv[0] * (av[0] + bb) + xv[1] * (av[1] + bb)
                + xv[2] * (av[2] + bb) + xv[3] * (av[3] + bb);
    }
    #pragma unroll
    for (int g = 0; g < 8; ++g) {
        accg[g] += __shfl_xor(accg[g], 32, 64);
        accg[g] += __shfl_xor(accg[g], 16, 64);
        accg[g] += __shfl_xor(accg[g], 8, 64);
        accg[g] += __shfl_xor(accg[g], 4, 64);
        accg[g] += __shfl_xor(accg[g], 2, 64);
        accg[g] += __shfl_xor(accg[g], 1, 64);
    }
    if (l == 0) {
        #pragma unroll
        for (int g = 0; g < 8; ++g)
            out[(size_t)gidx * 8 + g] = accg[g] * (1.0f / 256.0f);
    }
}

extern "C" void kernel_launch(void* const* d_in, const int* in_sizes, int n_in,
                              void* d_out, int out_size, void* d_ws, size_t ws_size,
                              hipStream_t stream) {
    const float* x  = (const float*)d_in[0];   // [32,768,16,16]
    const float* W1 = (const float*)d_in[1];   // [8,1536,768]
    const float* b1 = (const float*)d_in[2];   // [8,1536]
    const float* W2 = (const float*)d_in[3];   // [8,1536]
    const float* b2 = (const float*)d_in[4];   // [8]
    float* out = (float*)d_out;                // [32,768,8]

    char* ws = (char*)d_ws;
    bf16_t* W1bf = (bf16_t*)ws;                              // 9437184 * 2 B
    bf16_t* xTbf = (bf16_t*)(ws + 18874368);                 // 6291456 * 2 B
    float*  attn = (float*)(ws + 18874368 + 12582912);       // 65536 * 4 B

    hipFuncSetAttribute((const void*)k_attn_gemm,
                        hipFuncAttributeMaxDynamicSharedMemorySize, 148480);

    k_prep<<<dim3(10816), dim3(256), 0, stream>>>(W1, W1bf, x, xTbf, attn);
    k_attn_gemm<<<dim3(3072), dim3(512), 148480, stream>>>(W1bf, xTbf, b1, W2, attn);
    k_pool<<<dim3(6144), dim3(256), 0, stream>>>(x, attn, b2, out);
}

// Round 9
// 333.945 us; speedup vs baseline: 1.0615x; 1.0615x over previous
//
#include <hip/hip_runtime.h>
#include <hip/hip_bf16.h>
#include <cstdint>
#include <cstddef>

typedef __bf16 bf16_t;
typedef __bf16 bf16x8 __attribute__((ext_vector_type(8)));
typedef __bf16 bf16x4 __attribute__((ext_vector_type(4)));
typedef float  f32x4  __attribute__((ext_vector_type(4)));
typedef float  f32x16 __attribute__((ext_vector_type(16)));

#define AS1(p) ((const __attribute__((address_space(1))) unsigned int*)(p))
#define AS3(p) ((__attribute__((address_space(3))) unsigned int*)(p))

#if __has_builtin(__builtin_amdgcn_rcpf)
  #define FAST_RCP(x) __builtin_amdgcn_rcpf(x)
#else
  #define FAST_RCP(x) (1.0f / (x))
#endif

// Fast exact-gelu: Phi(v) via Abramowitz-Stegun 7.1.26 erf (|err| <= 1.5e-7).
__device__ __forceinline__ float gelu_fast(float v) {
    float z = fabsf(v) * 0.70710678118654752440f;
    float t = FAST_RCP(fmaf(0.3275911f, z, 1.0f));
    float p = fmaf(t, 1.061405429f, -1.453152027f);
    p = fmaf(t, p, 1.421413741f);
    p = fmaf(t, p, -0.284496736f);
    p = fmaf(t, p, 0.254829592f);
    p *= t;
    float e = p * exp2f(-z * z * 1.4426950408889634f);
    float phi = (v >= 0.0f) ? fmaf(-0.5f, e, 1.0f) : (0.5f * e);
    return v * phi;
}

// ---------- fused prep ----------
// bx < 4608  : pack W1 f32 -> bf16 in MFMA A-fragment order:
//              Apack[g][rb=d>>5][ks=k>>4][lane=(d&31)+32*((k>>3)&1)][j=k&7]
//              (1 KB contiguous per (rb,ks) fragment -> coalesced frag loads)
// bx < 6144  : x [B,C,HW] f32 -> xT [B,HW,C] bf16
// else       : zero attn workspace
__global__ void k_prep(const float* __restrict__ W1, bf16_t* __restrict__ Apack,
                       const float* __restrict__ x, bf16_t* __restrict__ xT,
                       float* __restrict__ attn) {
    __shared__ bf16_t t[64][66];
    int bx = blockIdx.x;
    int tid = threadIdx.x;
    if (bx < 4608) {
        int i = bx * 256 + tid;          // one thread = 8 consecutive k of one d
        int kc = i % 96;                 // k-octet 0..95
        int dg = i / 96;                 // g*1536 + d
        int d = dg % 1536, g = dg / 1536;
        const float* src = W1 + (size_t)dg * 768 + kc * 8;
        f32x4 v0 = *(const f32x4*)src;
        f32x4 v1 = *(const f32x4*)(src + 4);
        bf16x8 o;
        o[0] = (bf16_t)v0[0]; o[1] = (bf16_t)v0[1];
        o[2] = (bf16_t)v0[2]; o[3] = (bf16_t)v0[3];
        o[4] = (bf16_t)v1[0]; o[5] = (bf16_t)v1[1];
        o[6] = (bf16_t)v1[2]; o[7] = (bf16_t)v1[3];
        size_t dst = ((size_t)(g * 48 + (d >> 5)) * 48 + (kc >> 1)) * 512
                   + ((d & 31) + 32 * (kc & 1)) * 8;
        *(bf16x8*)(Apack + dst) = o;
        return;
    }
    if (bx >= 6144) {   // 64 blocks zero attn (65536 f32)
        int i = (bx - 6144) * 256 + tid;
        ((f32x4*)attn)[i] = f32x4{0.f, 0.f, 0.f, 0.f};
        return;
    }
    int bx2 = bx - 4608;
    int ct = bx2 % 12, ht = (bx2 / 12) % 4, b = bx2 / 48;
    int col = tid & 63, rr = tid >> 6;
    const float* xb = x + ((size_t)b * 768 + (size_t)ct * 64) * 256 + ht * 64;
    #pragma unroll
    for (int r = 0; r < 16; ++r) {
        int c = r * 4 + rr;
        t[c][col] = (bf16_t)xb[(size_t)c * 256 + col];
    }
    __syncthreads();
    bf16_t* xTb = xT + ((size_t)b * 256 + (size_t)ht * 64) * 768 + ct * 64;
    #pragma unroll
    for (int r = 0; r < 16; ++r) {
        int hw = r * 4 + rr;
        xTb[(size_t)hw * 768 + col] = t[col][hw];
    }
}

// ---------- fused grouped-GEMM + bias + fast-gelu + W2 reduction -> attn partials ----------
// Block 256M x 256N, 8 waves as 4M x 2N, per-wave 2x4 blocking (64x128).
// A (W1) comes fragment-packed from global/L2 — NO LDS for A. B (xT) double-buffered
// in LDS (2 x 32 KB), chunk^(row&7) swizzle, source-pre-swizzled (rule #21).
// One __syncthreads per K-tile: sync -> stage B(t+1) -> compute(t); the stage has a
// full tile to land so the next sync's implicit vmcnt(0) drain is ~free (T14 pattern).
// Per-CU per-tile: MFMA 2048 cyc > ds_read 1536 cyc -> MFMA-bound (was 1024 vs 1536+).
__global__ __launch_bounds__(512, 2) void k_attn_gemm(
    const bf16_t* __restrict__ Apack, const bf16_t* __restrict__ xTbf,
    const float* __restrict__ b1, const float* __restrict__ W2,
    float* __restrict__ attn)
{
    extern __shared__ char smem[];                 // Bs0 @0 (32K) | Bs1 @32768 | attn_s @65536
    float* attn_s = (float*)(smem + 65536);

    const int tid = threadIdx.x;
    const int l = tid & 63, w = tid >> 6;
    const int wm = w >> 1, wn = w & 1;             // 4 M-waves x 2 N-waves
    const int bid = blockIdx.x;
    const int g     = bid & 7;                     // group == XCD (T1)
    const int local = bid >> 3;                    // 0..191 = 6 mt x 32 b
    const int chunk = local / 12;                  // 16 chunks of 2 b's
    const int sub   = local % 12;
    const int mt    = sub >> 1;                    // 0..5
    const int b     = chunk * 2 + (sub & 1);

    const bf16_t* gB = xTbf + (size_t)b * 256 * 768;
    // per-wave A fragment pointer (lane offset baked in); mi=1 at +48*512 elems
    const bf16_t* pA = Apack + ((size_t)(g * 48 + mt * 8 + wm * 2) * 48) * 512 + l * 8;

    if (tid < 256) attn_s[tid] = 0.0f;

    // ---- hoisted B staging offsets (per-lane, tile-invariant) ----
    int voffB[4]; int ldsB[4];
    #pragma unroll
    for (int i = 0; i < 4; ++i) {
        int q = i * 512 + tid, row = q >> 3, sc = (q & 7) ^ (row & 7);
        voffB[i] = row * 768 + sc * 8;
        ldsB[i] = q * 16;
    }

    // ---- hoisted B LDS read offsets (tile-invariant, buffer-relative) ----
    // B-frag: n-row = wn*128 + ni*32 + (l&31), k-chunk c = s*2 + (l>>5)
    const int hi = l >> 5;
    uint32_t boff[4][4];
    #pragma unroll
    for (int s = 0; s < 4; ++s) {
        const int c = s * 2 + hi;
        #pragma unroll
        for (int ni = 0; ni < 4; ++ni) {
            int r = wn * 128 + ni * 32 + (l & 31);
            boff[s][ni] = (uint32_t)((r * 8 + (c ^ (r & 7))) * 16);
        }
    }

    f32x16 acc[2][4];
    #pragma unroll
    for (int mi = 0; mi < 2; ++mi)
        #pragma unroll
        for (int ni = 0; ni < 4; ++ni)
            acc[mi][ni] = (f32x16)(0.0f);

    auto STAGE = [&](int bufbase, int t) {
        #pragma unroll
        for (int i = 0; i < 4; ++i)
            __builtin_amdgcn_global_load_lds(AS1(gB + voffB[i] + t * 64),
                AS3(smem + bufbase + ldsB[i]), 16, 0, 0);
    };

    // ---- K-loop: 12 tiles of 64, fully unrolled; ONE barrier per tile ----
    STAGE(0, 0);
    #pragma unroll
    for (int t = 0; t < 12; ++t) {
        __syncthreads();                           // B(t) landed (staged a full tile ago)
        if (t < 11) STAGE(((t + 1) & 1) * 32768, t + 1);   // overlaps compute below
        const int bufb = (t & 1) * 32768;
        #pragma unroll
        for (int s = 0; s < 4; ++s) {
            // A fragments straight from L2 (fragment-packed, coalesced 1 KB/load)
            bf16x8 a0 = *(const bf16x8*)(pA + (t * 4 + s) * 512);
            bf16x8 a1 = *(const bf16x8*)(pA + 48 * 512 + (t * 4 + s) * 512);
            bf16x8 bb[4];
            #pragma unroll
            for (int ni = 0; ni < 4; ++ni)
                bb[ni] = *(const bf16x8*)(smem + bufb + boff[s][ni]);
            #pragma unroll
            for (int ni = 0; ni < 4; ++ni)
                acc[0][ni] = __builtin_amdgcn_mfma_f32_32x32x16_bf16(
                    a0, bb[ni], acc[0][ni], 0, 0, 0);
            #pragma unroll
            for (int ni = 0; ni < 4; ++ni)
                acc[1][ni] = __builtin_amdgcn_mfma_f32_32x32x16_bf16(
                    a1, bb[ni], acc[1][ni], 0, 0, 0);
        }
    }

    // ---- epilogue: bias + gelu + W2 dot over the 64 local D-rows per wave ----
    // 32x32 C/D: col = l&31, row = (rg&3) + 8*(rg>>2) + 4*(l>>5)  [m74/m101]
    float partial[4] = {0.f, 0.f, 0.f, 0.f};
    #pragma unroll
    for (int mi = 0; mi < 2; ++mi) {
        const int dbase = g * 1536 + mt * 256 + wm * 64 + mi * 32 + hi * 4;
        #pragma unroll
        for (int rq = 0; rq < 4; ++rq) {
            f32x4 b1v = *(const f32x4*)&b1[dbase + rq * 8];
            f32x4 w2v = *(const f32x4*)&W2[dbase + rq * 8];
            #pragma unroll
            for (int j = 0; j < 4; ++j) {
                const int rg = rq * 4 + j;
                #pragma unroll
                for (int ni = 0; ni < 4; ++ni) {
                    float h = acc[mi][ni][rg] + b1v[j];
                    partial[ni] += gelu_fast(h) * w2v[j];
                }
            }
        }
    }
    #pragma unroll
    for (int ni = 0; ni < 4; ++ni)
        partial[ni] += __shfl_xor(partial[ni], 32, 64);
    if (l < 32) {
        #pragma unroll
        for (int ni = 0; ni < 4; ++ni)
            atomicAdd(&attn_s[wn * 128 + ni * 32 + l], partial[ni]);
    }
    __syncthreads();
    if (tid < 256)
        atomicAdd(&attn[((size_t)b * 8 + g) * 256 + tid], attn_s[tid]);
}

// ---------- weighted mean pool ----------
__global__ void k_pool(const float* __restrict__ x, const float* __restrict__ attn,
                       const float* __restrict__ b2, float* __restrict__ out)
{
    int tid = threadIdx.x;
    int l = tid & 63, w = tid >> 6;
    int gidx = blockIdx.x * 4 + w;
    int b = gidx / 768;
    f32x4 xv = ((const f32x4*)(x + (size_t)gidx * 256))[l];
    float accg[8];
    #pragma unroll
    for (int g = 0; g < 8; ++g) {
        f32x4 av = ((const f32x4*)(attn + ((size_t)b * 8 + g) * 256))[l];
        float bb = b2[g];
        accg[g] = xv[0] * (av[0] + bb) + xv[1] * (av[1] + bb)
                + xv[2] * (av[2] + bb) + xv[3] * (av[3] + bb);
    }
    #pragma unroll
    for (int g = 0; g < 8; ++g) {
        accg[g] += __shfl_xor(accg[g], 32, 64);
        accg[g] += __shfl_xor(accg[g], 16, 64);
        accg[g] += __shfl_xor(accg[g], 8, 64);
        accg[g] += __shfl_xor(accg[g], 4, 64);
        accg[g] += __shfl_xor(accg[g], 2, 64);
        accg[g] += __shfl_xor(accg[g], 1, 64);
    }
    if (l == 0) {
        #pragma unroll
        for (int g = 0; g < 8; ++g)
            out[(size_t)gidx * 8 + g] = accg[g] * (1.0f / 256.0f);
    }
}

extern "C" void kernel_launch(void* const* d_in, const int* in_sizes, int n_in,
                              void* d_out, int out_size, void* d_ws, size_t ws_size,
                              hipStream_t stream) {
    const float* x  = (const float*)d_in[0];   // [32,768,16,16]
    const float* W1 = (const float*)d_in[1];   // [8,1536,768]
    const float* b1 = (const float*)d_in[2];   // [8,1536]
    const float* W2 = (const float*)d_in[3];   // [8,1536]
    const float* b2 = (const float*)d_in[4];   // [8]
    float* out = (float*)d_out;                // [32,768,8]

    char* ws = (char*)d_ws;
    bf16_t* Apack = (bf16_t*)ws;                             // 9437184 * 2 B
    bf16_t* xTbf  = (bf16_t*)(ws + 18874368);                // 6291456 * 2 B
    float*  attn  = (float*)(ws + 18874368 + 12582912);      // 65536 * 4 B

    hipFuncSetAttribute((const void*)k_attn_gemm,
                        hipFuncAttributeMaxDynamicSharedMemorySize, 66560);

    k_prep<<<dim3(6208), dim3(256), 0, stream>>>(W1, Apack, x, xTbf, attn);
    k_attn_gemm<<<dim3(1536), dim3(512), 66560, stream>>>(Apack, xTbf, b1, W2, attn);
    k_pool<<<dim3(6144), dim3(256), 0, stream>>>(x, attn, b2, out);
}

// Round 12
// 304.140 us; speedup vs baseline: 1.1655x; 1.0980x over previous
//
#include <hip/hip_runtime.h>
#include <hip/hip_bf16.h>
#include <cstdint>
#include <cstddef>

typedef __bf16 bf16_t;
typedef __bf16 bf16x8 __attribute__((ext_vector_type(8)));
typedef __bf16 bf16x4 __attribute__((ext_vector_type(4)));
typedef float  f32x4  __attribute__((ext_vector_type(4)));
typedef float  f32x16 __attribute__((ext_vector_type(16)));

#define AS1(p) ((const __attribute__((address_space(1))) unsigned int*)(p))
#define AS3(p) ((__attribute__((address_space(3))) unsigned int*)(p))

#if __has_builtin(__builtin_amdgcn_rcpf)
  #define FAST_RCP(x) __builtin_amdgcn_rcpf(x)
#else
  #define FAST_RCP(x) (1.0f / (x))
#endif

// Fast exact-gelu: Phi(v) via Abramowitz-Stegun 7.1.26 erf (|err| <= 1.5e-7).
__device__ __forceinline__ float gelu_fast(float v) {
    float z = fabsf(v) * 0.70710678118654752440f;
    float t = FAST_RCP(fmaf(0.3275911f, z, 1.0f));
    float p = fmaf(t, 1.061405429f, -1.453152027f);
    p = fmaf(t, p, 1.421413741f);
    p = fmaf(t, p, -0.284496736f);
    p = fmaf(t, p, 0.254829592f);
    p *= t;
    float e = p * exp2f(-z * z * 1.4426950408889634f);
    float phi = (v >= 0.0f) ? fmaf(-0.5f, e, 1.0f) : (0.5f * e);
    return v * phi;
}

// ---------- fused prep ----------
// bx < 4608  : pack W1 f32 -> bf16 in MFMA A-fragment order:
//              Apack[g][rb=d>>5][ks=k>>4][lane=(d&31)+32*((k>>3)&1)][j=k&7]
// bx < 6144  : x [B,C,HW] f32 -> xT [B,HW,C] bf16
// else       : zero attn workspace
__global__ void k_prep(const float* __restrict__ W1, bf16_t* __restrict__ Apack,
                       const float* __restrict__ x, bf16_t* __restrict__ xT,
                       float* __restrict__ attn) {
    __shared__ bf16_t t[64][66];
    int bx = blockIdx.x;
    int tid = threadIdx.x;
    if (bx < 4608) {
        int i = bx * 256 + tid;          // one thread = 8 consecutive k of one d
        int kc = i % 96;                 // k-octet 0..95
        int dg = i / 96;                 // g*1536 + d
        int d = dg % 1536, g = dg / 1536;
        const float* src = W1 + (size_t)dg * 768 + kc * 8;
        f32x4 v0 = *(const f32x4*)src;
        f32x4 v1 = *(const f32x4*)(src + 4);
        bf16x8 o;
        o[0] = (bf16_t)v0[0]; o[1] = (bf16_t)v0[1];
        o[2] = (bf16_t)v0[2]; o[3] = (bf16_t)v0[3];
        o[4] = (bf16_t)v1[0]; o[5] = (bf16_t)v1[1];
        o[6] = (bf16_t)v1[2]; o[7] = (bf16_t)v1[3];
        size_t dst = ((size_t)(g * 48 + (d >> 5)) * 48 + (kc >> 1)) * 512
                   + ((d & 31) + 32 * (kc & 1)) * 8;
        *(bf16x8*)(Apack + dst) = o;
        return;
    }
    if (bx >= 6144) {   // 64 blocks zero attn (65536 f32)
        int i = (bx - 6144) * 256 + tid;
        ((f32x4*)attn)[i] = f32x4{0.f, 0.f, 0.f, 0.f};
        return;
    }
    int bx2 = bx - 4608;
    int ct = bx2 % 12, ht = (bx2 / 12) % 4, b = bx2 / 48;
    int col = tid & 63, rr = tid >> 6;
    const float* xb = x + ((size_t)b * 768 + (size_t)ct * 64) * 256 + ht * 64;
    #pragma unroll
    for (int r = 0; r < 16; ++r) {
        int c = r * 4 + rr;
        t[c][col] = (bf16_t)xb[(size_t)c * 256 + col];
    }
    __syncthreads();
    bf16_t* xTb = xT + ((size_t)b * 256 + (size_t)ht * 64) * 768 + ct * 64;
    #pragma unroll
    for (int r = 0; r < 16; ++r) {
        int hw = r * 4 + rr;
        xTb[(size_t)hw * 768 + col] = t[col][hw];
    }
}

// ---------- fused grouped-GEMM + bias + fast-gelu + W2 reduction -> attn partials ----------
// OCCUPANCY-FIRST: 256-thread blocks (4 waves 2Mx2N, wave 64x64 = 2x2 of 32x32),
// acc = 64 VGPR -> __launch_bounds__(256,4) => 4 blocks/CU = 4 waves/SIMD. Independent
// resident blocks hide A-load + barrier latency (m114/m97 mechanism).
// Dataflow (from R9): A fragment-packed from global (L2-resident per XCD, T1 g=bid&7),
// B-only in LDS (2x16 KB dbuf, chunk^(row&7) swizzle source-pre-swizzled), one
// __syncthreads per tile: sync -> stage B(t+1) -> compute(t).
__global__ __launch_bounds__(256, 4) void k_attn_gemm(
    const bf16_t* __restrict__ Apack, const bf16_t* __restrict__ xTbf,
    const float* __restrict__ b1, const float* __restrict__ W2,
    float* __restrict__ attn)
{
    extern __shared__ char smem[];                 // Bs0 @0 (16K) | Bs1 @16384 | attn_s @32768
    float* attn_s = (float*)(smem + 32768);

    const int tid = threadIdx.x;
    const int l = tid & 63, w = tid >> 6;
    const int wm = w >> 1, wn = w & 1;             // 2 M-waves x 2 N-waves
    const int bid = blockIdx.x;
    const int g     = bid & 7;                     // group == XCD (T1)
    const int local = bid >> 3;                    // 0..767 = 16 chunks x 48
    const int chunk = local / 48;                  // 16 chunks of 2 b's
    const int sub   = local % 48;                  // 12 mt x 2 b x 2 nt
    const int mt    = sub >> 2;                    // 0..11
    const int b     = chunk * 2 + ((sub >> 1) & 1);
    const int nt    = sub & 1;

    const bf16_t* gB = xTbf + ((size_t)b * 256 + nt * 128) * 768;
    // per-wave A fragment pointer: rb = mt*4 + wm*2 (+mi); stride per rb = 48*512
    const bf16_t* pA = Apack + ((size_t)(g * 48 + mt * 4 + wm * 2) * 48) * 512 + l * 8;

    if (tid < 128) attn_s[tid] = 0.0f;

    // ---- hoisted B staging offsets (per-lane, tile-invariant) ----
    int voffB[4]; int ldsB[4];
    #pragma unroll
    for (int i = 0; i < 4; ++i) {
        int q = i * 256 + tid, row = q >> 3, sc = (q & 7) ^ (row & 7);
        voffB[i] = row * 768 + sc * 8;
        ldsB[i] = q * 16;
    }

    // ---- hoisted B LDS read offsets (tile-invariant, buffer-relative) ----
    // B-frag: n-row = wn*64 + ni*32 + (l&31), k-chunk c = s*2 + (l>>5)
    const int hi = l >> 5;
    uint32_t boff[4][2];
    #pragma unroll
    for (int s = 0; s < 4; ++s) {
        const int c = s * 2 + hi;
        #pragma unroll
        for (int ni = 0; ni < 2; ++ni) {
            int r = wn * 64 + ni * 32 + (l & 31);
            boff[s][ni] = (uint32_t)((r * 8 + (c ^ (r & 7))) * 16);
        }
    }

    f32x16 acc[2][2];
    #pragma unroll
    for (int mi = 0; mi < 2; ++mi)
        #pragma unroll
        for (int ni = 0; ni < 2; ++ni)
            acc[mi][ni] = (f32x16)(0.0f);

    auto STAGE = [&](int bufbase, int t) {
        #pragma unroll
        for (int i = 0; i < 4; ++i)
            __builtin_amdgcn_global_load_lds(AS1(gB + voffB[i] + t * 64),
                AS3(smem + bufbase + ldsB[i]), 16, 0, 0);
    };

    // ---- K-loop: 12 tiles of 64, fully unrolled; ONE barrier per tile ----
    STAGE(0, 0);
    #pragma unroll
    for (int t = 0; t < 12; ++t) {
        __syncthreads();                           // B(t) landed (staged a full tile ago)
        if (t < 11) STAGE(((t + 1) & 1) * 16384, t + 1);   // lands under compute below
        const int bufb = (t & 1) * 16384;
        #pragma unroll
        for (int s = 0; s < 4; ++s) {
            bf16x8 a0 = *(const bf16x8*)(pA + (t * 4 + s) * 512);
            bf16x8 a1 = *(const bf16x8*)(pA + 48 * 512 + (t * 4 + s) * 512);
            bf16x8 bb[2];
            #pragma unroll
            for (int ni = 0; ni < 2; ++ni)
                bb[ni] = *(const bf16x8*)(smem + bufb + boff[s][ni]);
            #pragma unroll
            for (int ni = 0; ni < 2; ++ni)
                acc[0][ni] = __builtin_amdgcn_mfma_f32_32x32x16_bf16(
                    a0, bb[ni], acc[0][ni], 0, 0, 0);
            #pragma unroll
            for (int ni = 0; ni < 2; ++ni)
                acc[1][ni] = __builtin_amdgcn_mfma_f32_32x32x16_bf16(
                    a1, bb[ni], acc[1][ni], 0, 0, 0);
        }
    }

    // ---- epilogue: bias + gelu + W2 dot over the 64 local D-rows per wave ----
    // 32x32 C/D: col = l&31, row = (rg&3) + 8*(rg>>2) + 4*(l>>5)  [m74/m101]
    float partial[2] = {0.f, 0.f};
    #pragma unroll
    for (int mi = 0; mi < 2; ++mi) {
        const int dbase = g * 1536 + mt * 128 + wm * 64 + mi * 32 + hi * 4;
        #pragma unroll
        for (int rq = 0; rq < 4; ++rq) {
            f32x4 b1v = *(const f32x4*)&b1[dbase + rq * 8];
            f32x4 w2v = *(const f32x4*)&W2[dbase + rq * 8];
            #pragma unroll
            for (int j = 0; j < 4; ++j) {
                const int rg = rq * 4 + j;
                #pragma unroll
                for (int ni = 0; ni < 2; ++ni) {
                    float h = acc[mi][ni][rg] + b1v[j];
                    partial[ni] += gelu_fast(h) * w2v[j];
                }
            }
        }
    }
    #pragma unroll
    for (int ni = 0; ni < 2; ++ni)
        partial[ni] += __shfl_xor(partial[ni], 32, 64);
    if (l < 32) {
        #pragma unroll
        for (int ni = 0; ni < 2; ++ni)
            atomicAdd(&attn_s[wn * 64 + ni * 32 + l], partial[ni]);
    }
    __syncthreads();
    if (tid < 128)
        atomicAdd(&attn[((size_t)b * 8 + g) * 256 + nt * 128 + tid], attn_s[tid]);
}

// ---------- weighted mean pool ----------
__global__ void k_pool(const float* __restrict__ x, const float* __restrict__ attn,
                       const float* __restrict__ b2, float* __restrict__ out)
{
    int tid = threadIdx.x;
    int l = tid & 63, w = tid >> 6;
    int gidx = blockIdx.x * 4 + w;
    int b = gidx / 768;
    f32x4 xv = ((const f32x4*)(x + (size_t)gidx * 256))[l];
    float accg[8];
    #pragma unroll
    for (int g = 0; g < 8; ++g) {
        f32x4 av = ((const f32x4*)(attn + ((size_t)b * 8 + g) * 256))[l];
        float bb = b2[g];
        accg[g] = xv[0] * (av[0] + bb) + xv[1] * (av[1] + bb)
                + xv[2] * (av[2] + bb) + xv[3] * (av[3] + bb);
    }
    #pragma unroll
    for (int g = 0; g < 8; ++g) {
        accg[g] += __shfl_xor(accg[g], 32, 64);
        accg[g] += __shfl_xor(accg[g], 16, 64);
        accg[g] += __shfl_xor(accg[g], 8, 64);
        accg[g] += __shfl_xor(accg[g], 4, 64);
        accg[g] += __shfl_xor(accg[g], 2, 64);
        accg[g] += __shfl_xor(accg[g], 1, 64);
    }
    if (l == 0) {
        #pragma unroll
        for (int g = 0; g < 8; ++g)
            out[(size_t)gidx * 8 + g] = accg[g] * (1.0f / 256.0f);
    }
}

extern "C" void kernel_launch(void* const* d_in, const int* in_sizes, int n_in,
                              void* d_out, int out_size, void* d_ws, size_t ws_size,
                              hipStream_t stream) {
    const float* x  = (const float*)d_in[0];   // [32,768,16,16]
    const float* W1 = (const float*)d_in[1];   // [8,1536,768]
    const float* b1 = (const float*)d_in[2];   // [8,1536]
    const float* W2 = (const float*)d_in[3];   // [8,1536]
    const float* b2 = (const float*)d_in[4];   // [8]
    float* out = (float*)d_out;                // [32,768,8]

    char* ws = (char*)d_ws;
    bf16_t* Apack = (bf16_t*)ws;                             // 9437184 * 2 B
    bf16_t* xTbf  = (bf16_t*)(ws + 18874368);                // 6291456 * 2 B
    float*  attn  = (float*)(ws + 18874368 + 12582912);      // 65536 * 4 B

    hipFuncSetAttribute((const void*)k_attn_gemm,
                        hipFuncAttributeMaxDynamicSharedMemorySize, 33280);

    k_prep<<<dim3(6208), dim3(256), 0, stream>>>(W1, Apack, x, xTbf, attn);
    k_attn_gemm<<<dim3(6144), dim3(256), 33280, stream>>>(Apack, xTbf, b1, W2, attn);
    k_pool<<<dim3(6144), dim3(256), 0, stream>>>(x, attn, b2, out);
}